// Round 6
// baseline (435.366 us; speedup 1.0000x reference)
//
#include <hip/hip_runtime.h>
#include <hip/hip_bf16.h>

#define N_NODES  100000
#define N_EDGES  1600000
#define D_FEAT   128
#define N_GRAPHS 128
#define N_CLS    10
#define CAP      64
#define ZROW     100000   // dedicated all-zero fp8 row

#define NB       391      // buckets of 256 dst nodes (391*256 = 100096)
#define CAPB     4608     // staging capacity per bucket
#define CHUNK    8000     // edges per binsort block
#define PCHUNK   128      // nodes per pool_partial block

typedef __bf16 bf16x8 __attribute__((ext_vector_type(8)));
typedef float  f32x4  __attribute__((ext_vector_type(4)));
typedef float  f32x2  __attribute__((ext_vector_type(2)));

// ---------------- W transpose + bf16 convert (Wt[n][k]) + zero-row init ----------------
__global__ __launch_bounds__(256) void prepW(const float* __restrict__ W0,
                                             const float* __restrict__ W1,
                                             const float* __restrict__ W2,
                                             __bf16* __restrict__ wt,
                                             unsigned char* __restrict__ Hs) {
    int idx = blockIdx.x * 256 + threadIdx.x;
    if (blockIdx.x == 0 && threadIdx.x < 32)
        ((unsigned int*)(Hs + (size_t)ZROW * 128))[threadIdx.x] = 0u;
    if (idx >= 3 * 16384) return;
    int which = idx >> 14, e = idx & 16383;
    int k = e >> 7, n = e & 127;
    const float* W = (which == 0) ? W0 : ((which == 1) ? W1 : W2);
    wt[which * 16384 + n * 128 + k] = (__bf16)W[k * 128 + n];
}

// ---------------- pass 1: block-local counting sort of edges by dst bucket ----------------
__global__ __launch_bounds__(512) void binsort(const int* __restrict__ ei,
                                               int* __restrict__ gcur,
                                               int* __restrict__ staging) {
    __shared__ int hist[512];
    __shared__ int hscan[512];
    __shared__ int cur[512];
    __shared__ int gofs[512];
    __shared__ uint2 lbuf[CHUNK];   // 64 KB
    int t = threadIdx.x;
    int base = blockIdx.x * CHUNK;

    hist[t] = 0;
    __syncthreads();
    for (int i = t; i < CHUNK; i += 512)
        atomicAdd(&hist[ei[N_EDGES + base + i] >> 8], 1);
    __syncthreads();
    hscan[t] = hist[t];
    __syncthreads();
    for (int off = 1; off < 512; off <<= 1) {
        int v = (t >= off) ? hscan[t - off] : 0;
        __syncthreads();
        hscan[t] += v;
        __syncthreads();
    }
    int ex = hscan[t] - hist[t];
    cur[t] = ex;
    if (t < NB && hist[t] > 0) {
        int gb = atomicAdd(&gcur[t], hist[t]);
        gofs[t] = t * CAPB + gb - ex;
    }
    __syncthreads();
    for (int i = t; i < CHUNK; i += 512) {
        unsigned src = (unsigned)ei[base + i];
        unsigned dst = (unsigned)ei[N_EDGES + base + i];
        int p = atomicAdd(&cur[dst >> 8], 1);
        lbuf[p] = make_uint2(src, dst);
    }
    __syncthreads();
    for (int i = t; i < CHUNK; i += 512) {
        uint2 v = lbuf[i];
        int b = (int)(v.y >> 8);
        staging[gofs[b] + i] = (int)(((v.y & 255u) << 24) | v.x);
    }
}

// ---------------- pass 2: per-bucket srclist build, 4-way src-quarter partitioned ----------------
// Each node's list ends up grouped by src quarter (src>>15): 3.2 MB windows ~ L2-sized,
// so concurrent aggregate waves sweep the same window in phase.
__global__ __launch_bounds__(256) void build_csr(const int* __restrict__ gcur,
                                                 const int* __restrict__ staging,
                                                 int* __restrict__ srclist,
                                                 int* __restrict__ cnt,
                                                 float* __restrict__ dinv) {
    __shared__ int slots[256 * CAP];   // 64 KB
    __shared__ int c4[4 * 256];        // 4 KB: per-node per-quarter counters
    int t = threadIdx.x, b = blockIdx.x;
#pragma unroll
    for (int q = 0; q < 4; ++q) c4[q * 256 + t] = 0;
    __syncthreads();
    int cb = gcur[b];
    if (cb > CAPB) cb = CAPB;
    const int* st = staging + b * CAPB;
    // pass A: count per (node, src-quarter)
    for (int i = t; i < cb; i += 256) {
        int v = st[i];
        int ld = ((unsigned)v) >> 24;
        int s = v & 0xFFFFFF;
        atomicAdd(&c4[(s >> 15) * 256 + ld], 1);
    }
    __syncthreads();
    // thread t owns node t's 4 counters: convert to running bases
    int q0 = c4[t], q1 = c4[256 + t], q2 = c4[512 + t];
    int total = q0 + q1 + q2 + c4[768 + t];
    c4[t] = 0;
    c4[256 + t] = q0;
    c4[512 + t] = q0 + q1;
    c4[768 + t] = q0 + q1 + q2;
    __syncthreads();
    // pass B: place (staging re-read is L2-hot)
    for (int i = t; i < cb; i += 256) {
        int v = st[i];
        int ld = ((unsigned)v) >> 24;
        int s = v & 0xFFFFFF;
        int p = atomicAdd(&c4[(s >> 15) * 256 + ld], 1);
        if (p < CAP) slots[ld * CAP + p] = s;
    }
    __syncthreads();
    int4* d4 = (int4*)(srclist + (size_t)b * 256 * CAP);
    const int4* s4 = (const int4*)slots;
    for (int j = t; j < 256 * CAP / 4; j += 256) d4[j] = s4[j];
    int node = b * 256 + t;
    if (node < N_NODES) {
        cnt[node] = total;
        dinv[node] = rsqrtf((float)total + 1.0f);
    }
}

// ---------------- GEMM: Hs[row] = fp8(dinv[row] * (A @ W)[row]), bf16 MFMA ----------------
template <bool A_IS_F32>
__global__ __launch_bounds__(256) void gemm128(const void* __restrict__ Ap,
                                               const __bf16* __restrict__ Wt,
                                               const float* __restrict__ dinv,
                                               unsigned char* __restrict__ Hs) {
    int wid = (blockIdx.x * 256 + threadIdx.x) >> 6;
    if (wid >= N_NODES / 16) return;
    int lane = threadIdx.x & 63;
    int m = lane & 15, q = lane >> 4;
    int rowbase = wid * 16;

    f32x4 acc[8] = {};

#pragma unroll
    for (int ks = 0; ks < 4; ++ks) {
        bf16x8 a;
        if (A_IS_F32) {
            const float* A = (const float*)Ap + (size_t)(rowbase + m) * 128 + ks * 32 + q * 8;
            f32x4 v0 = *(const f32x4*)A;
            f32x4 v1 = *(const f32x4*)(A + 4);
            a[0] = (__bf16)v0[0]; a[1] = (__bf16)v0[1];
            a[2] = (__bf16)v0[2]; a[3] = (__bf16)v0[3];
            a[4] = (__bf16)v1[0]; a[5] = (__bf16)v1[1];
            a[6] = (__bf16)v1[2]; a[7] = (__bf16)v1[3];
        } else {
            a = *(const bf16x8*)((const __bf16*)Ap + (size_t)(rowbase + m) * 128 + ks * 32 + q * 8);
        }
#pragma unroll
        for (int tj = 0; tj < 8; ++tj) {
            bf16x8 b = *(const bf16x8*)(Wt + (tj * 16 + m) * 128 + ks * 32 + q * 8);
            acc[tj] = __builtin_amdgcn_mfma_f32_16x16x32_bf16(a, b, acc[tj], 0, 0, 0);
        }
    }

    float dv[4];
#pragma unroll
    for (int r = 0; r < 4; ++r) dv[r] = dinv[rowbase + q * 4 + r];
#pragma unroll
    for (int tj = 0; tj < 8; ++tj) {
#pragma unroll
        for (int r = 0; r < 4; ++r) {
            float val = acc[tj][r] * dv[r];
            int pk = __builtin_amdgcn_cvt_pk_fp8_f32(val, val, 0, false);
            Hs[(size_t)(rowbase + q * 4 + r) * 128 + tj * 16 + m] = (unsigned char)(pk & 0xFF);
        }
    }
}

// ---------------- aggregation: one wave per dst node, 8 edges/iter, fp8 gather ----------------
// lanes: g = lane>>3 (edge slot 0..7), idx = lane&7 (bytes idx*16..idx*16+15 of the row)
template <bool RELU>
__global__ __launch_bounds__(256) void aggregate(const unsigned char* __restrict__ Hs,
                                                 const float* __restrict__ bias,
                                                 const float* __restrict__ dinv,
                                                 const int* __restrict__ cnt,
                                                 const int* __restrict__ srclist,
                                                 __bf16* __restrict__ X) {
    int node = blockIdx.x * 4 + (threadIdx.x >> 6);
    int lane = threadIdx.x & 63;
    int g = lane >> 3;
    int idx = lane & 7;
    float di = dinv[node];
    int deg = cnt[node];
    if (deg > CAP) deg = CAP;
    const int* lst = srclist + (size_t)node * CAP;

    f32x2 acc[8] = {};

    // depth-1 software pipeline, 8 edges per iteration
    int s = (g < deg) ? lst[g] : ZROW;
    uint4 v = *(const uint4*)(Hs + (size_t)s * 128 + idx * 16);
    for (int e = 0; e < deg; e += 8) {
        int en = e + 8 + g;
        int sn = (en < deg) ? lst[en] : ZROW;
        uint4 vn = *(const uint4*)(Hs + (size_t)sn * 128 + idx * 16);
        acc[0] += __builtin_amdgcn_cvt_pk_f32_fp8(v.x, false);
        acc[1] += __builtin_amdgcn_cvt_pk_f32_fp8(v.x, true);
        acc[2] += __builtin_amdgcn_cvt_pk_f32_fp8(v.y, false);
        acc[3] += __builtin_amdgcn_cvt_pk_f32_fp8(v.y, true);
        acc[4] += __builtin_amdgcn_cvt_pk_f32_fp8(v.z, false);
        acc[5] += __builtin_amdgcn_cvt_pk_f32_fp8(v.z, true);
        acc[6] += __builtin_amdgcn_cvt_pk_f32_fp8(v.w, false);
        acc[7] += __builtin_amdgcn_cvt_pk_f32_fp8(v.w, true);
        v = vn;
    }

    // reduce across the 8 edge-groups (lane bits 3,4,5)
#pragma unroll
    for (int j = 0; j < 8; ++j) {
        float a0 = acc[j][0], a1 = acc[j][1];
        a0 += __shfl_xor(a0, 8);  a1 += __shfl_xor(a1, 8);
        a0 += __shfl_xor(a0, 16); a1 += __shfl_xor(a1, 16);
        a0 += __shfl_xor(a0, 32); a1 += __shfl_xor(a1, 32);
        acc[j][0] = a0; acc[j][1] = a1;
    }

    // self-loop term: + Hs[node] (already scaled by dinv[node])
    uint4 hv = *(const uint4*)(Hs + (size_t)node * 128 + idx * 16);
    acc[0] += __builtin_amdgcn_cvt_pk_f32_fp8(hv.x, false);
    acc[1] += __builtin_amdgcn_cvt_pk_f32_fp8(hv.x, true);
    acc[2] += __builtin_amdgcn_cvt_pk_f32_fp8(hv.y, false);
    acc[3] += __builtin_amdgcn_cvt_pk_f32_fp8(hv.y, true);
    acc[4] += __builtin_amdgcn_cvt_pk_f32_fp8(hv.z, false);
    acc[5] += __builtin_amdgcn_cvt_pk_f32_fp8(hv.z, true);
    acc[6] += __builtin_amdgcn_cvt_pk_f32_fp8(hv.w, false);
    acc[7] += __builtin_amdgcn_cvt_pk_f32_fp8(hv.w, true);

    f32x4 bb0 = *(const f32x4*)(bias + idx * 16);
    f32x4 bb1 = *(const f32x4*)(bias + idx * 16 + 4);
    f32x4 bb2 = *(const f32x4*)(bias + idx * 16 + 8);
    f32x4 bb3 = *(const f32x4*)(bias + idx * 16 + 12);
    float bv[16] = {bb0[0], bb0[1], bb0[2], bb0[3], bb1[0], bb1[1], bb1[2], bb1[3],
                    bb2[0], bb2[1], bb2[2], bb2[3], bb3[0], bb3[1], bb3[2], bb3[3]};

    bf16x8 o0, o1;
#pragma unroll
    for (int j = 0; j < 4; ++j) {
        float t0 = di * acc[j][0] + bv[j * 2 + (j & ~1) * 0 + 0];  // placeholder, fixed below
        (void)t0;
    }
    // dims for lane: idx*16 + 4*k + {0,1} in acc[2k], {2,3} in acc[2k+1]
#pragma unroll
    for (int k = 0; k < 2; ++k) {
        float t0 = di * acc[2 * k][0]     + bv[4 * k + 0];
        float t1 = di * acc[2 * k][1]     + bv[4 * k + 1];
        float t2 = di * acc[2 * k + 1][0] + bv[4 * k + 2];
        float t3 = di * acc[2 * k + 1][1] + bv[4 * k + 3];
        if (RELU) { t0 = fmaxf(t0, 0.f); t1 = fmaxf(t1, 0.f); t2 = fmaxf(t2, 0.f); t3 = fmaxf(t3, 0.f); }
        o0[4 * k + 0] = (__bf16)t0; o0[4 * k + 1] = (__bf16)t1;
        o0[4 * k + 2] = (__bf16)t2; o0[4 * k + 3] = (__bf16)t3;
    }
#pragma unroll
    for (int k = 2; k < 4; ++k) {
        float t0 = di * acc[2 * k][0]     + bv[4 * k + 0];
        float t1 = di * acc[2 * k][1]     + bv[4 * k + 1];
        float t2 = di * acc[2 * k + 1][0] + bv[4 * k + 2];
        float t3 = di * acc[2 * k + 1][1] + bv[4 * k + 3];
        if (RELU) { t0 = fmaxf(t0, 0.f); t1 = fmaxf(t1, 0.f); t2 = fmaxf(t2, 0.f); t3 = fmaxf(t3, 0.f); }
        o1[4 * (k - 2) + 0] = (__bf16)t0; o1[4 * (k - 2) + 1] = (__bf16)t1;
        o1[4 * (k - 2) + 2] = (__bf16)t2; o1[4 * (k - 2) + 3] = (__bf16)t3;
    }
    if (g == 0) {
        *(bf16x8*)(X + (size_t)node * 128 + idx * 16) = o0;
        *(bf16x8*)(X + (size_t)node * 128 + idx * 16 + 8) = o1;
    }
}

// ---------------- pooling stage 1: per-chunk fp32 partial sums, atomic flush ----------------
__global__ __launch_bounds__(256) void pool_partial(const __bf16* __restrict__ X,
                                                    const int* __restrict__ batch,
                                                    float* __restrict__ sums) {
    int t = threadIdx.x;
    int d = t & 127, half = t >> 7;
    int start = blockIdx.x * PCHUNK;
    int end = start + PCHUNK;
    if (end > N_NODES) end = N_NODES;
    float acc = 0.f;
    int curg = -1;
    for (int i = start + half; i < end; i += 2) {
        int g = batch[i];
        if (g != curg) {
            if (curg >= 0) atomicAdd(&sums[curg * 128 + d], acc);
            acc = 0.f;
            curg = g;
        }
        acc += (float)X[(size_t)i * 128 + d];
    }
    if (curg >= 0) atomicAdd(&sums[curg * 128 + d], acc);
}

// ---------------- pooling stage 2: divide, linear, softmax ----------------
__global__ __launch_bounds__(64) void pool_final(const float* __restrict__ sums,
                                                 const int* __restrict__ batch,
                                                 const float* __restrict__ linW,
                                                 const float* __restrict__ linb,
                                                 float* __restrict__ out) {
    int g = blockIdx.x, lane = threadIdx.x;
    int bnd[2];
#pragma unroll
    for (int k = 0; k < 2; ++k) {
        int target = g + k;
        int lo = 0, hi = N_NODES;
        while (lo < hi) {
            int mid = (lo + hi) >> 1;
            if (batch[mid] < target) lo = mid + 1; else hi = mid;
        }
        bnd[k] = lo;
    }
    float c = fmaxf((float)(bnd[1] - bnd[0]), 1.f);
    float p0 = sums[g * 128 + lane] / c;
    float p1 = sums[g * 128 + 64 + lane] / c;

    float lg[N_CLS];
#pragma unroll
    for (int cc = 0; cc < N_CLS; ++cc) {
        float v = p0 * linW[lane * N_CLS + cc] + p1 * linW[(lane + 64) * N_CLS + cc];
#pragma unroll
        for (int off = 1; off < 64; off <<= 1) v += __shfl_xor(v, off);
        lg[cc] = v + linb[cc];
    }
    float mx = -1e30f;
#pragma unroll
    for (int cc = 0; cc < N_CLS; ++cc) mx = fmaxf(mx, lg[cc]);
    float ssum = 0.f;
#pragma unroll
    for (int cc = 0; cc < N_CLS; ++cc) { lg[cc] = __expf(lg[cc] - mx); ssum += lg[cc]; }
    if (lane < N_CLS) out[g * N_CLS + lane] = lg[lane] / ssum;
}

extern "C" void kernel_launch(void* const* d_in, const int* in_sizes, int n_in,
                              void* d_out, int out_size, void* d_ws, size_t ws_size,
                              hipStream_t stream) {
    const float* x     = (const float*)d_in[0];
    const int*   ei    = (const int*)d_in[1];
    const int*   batch = (const int*)d_in[2];
    const float* W0    = (const float*)d_in[3];
    const float* b0    = (const float*)d_in[4];
    const float* W1    = (const float*)d_in[5];
    const float* b1    = (const float*)d_in[6];
    const float* W2    = (const float*)d_in[7];
    const float* b2    = (const float*)d_in[8];
    const float* linW  = (const float*)d_in[9];
    const float* linb  = (const float*)d_in[10];

    char* ws = (char*)d_ws;
    int*    gcur    = (int*)(ws + 0);             // 2048 B
    float*  sums    = (float*)(ws + 2048);        // 65536 B
    float*  dinv    = (float*)(ws + 67584);       // 400000 B
    int*    cnt     = (int*)(ws + 467584);        // 400000 B
    __bf16* wt      = (__bf16*)(ws + 867584);     // 98304 B
    int*    srclist = (int*)(ws + 965888);        // 25624576 B
    unsigned char* Hs = (unsigned char*)(ws + 26590464); // 12.8 MB fp8 (+ zero row)
    int*    staging = (int*)(ws + 26590464);      // 7.2 MB, aliases Hs (dead before gemm)
    __bf16* xbuf    = (__bf16*)(ws + 52190464);   // 25.6 MB

    hipMemsetAsync(ws, 0, 67584, stream);         // gcur + sums

    prepW<<<192, 256, 0, stream>>>(W0, W1, W2, wt, Hs);   // also zeroes Hs[ZROW]
    binsort<<<200, 512, 0, stream>>>(ei, gcur, staging);
    build_csr<<<NB, 256, 0, stream>>>(gcur, staging, srclist, cnt, dinv);

    // Layer 0
    gemm128<true><<<1563, 256, 0, stream>>>(x, wt, dinv, Hs);
    aggregate<true><<<N_NODES / 4, 256, 0, stream>>>(Hs, b0, dinv, cnt, srclist, xbuf);
    // Layer 1
    gemm128<false><<<1563, 256, 0, stream>>>(xbuf, wt + 16384, dinv, Hs);
    aggregate<true><<<N_NODES / 4, 256, 0, stream>>>(Hs, b1, dinv, cnt, srclist, xbuf);
    // Layer 2 (no relu)
    gemm128<false><<<1563, 256, 0, stream>>>(xbuf, wt + 32768, dinv, Hs);
    aggregate<false><<<N_NODES / 4, 256, 0, stream>>>(Hs, b2, dinv, cnt, srclist, xbuf);

    pool_partial<<<(N_NODES + PCHUNK - 1) / PCHUNK, 256, 0, stream>>>(xbuf, batch, sums);
    pool_final<<<N_GRAPHS, 64, 0, stream>>>(sums, batch, linW, linb, (float*)d_out);
}

// Round 7
// 428.252 us; speedup vs baseline: 1.0166x; 1.0166x over previous
//
#include <hip/hip_runtime.h>
#include <hip/hip_bf16.h>

#define N_NODES  100000
#define N_EDGES  1600000
#define D_FEAT   128
#define N_GRAPHS 128
#define N_CLS    10
#define CAP      64
#define ZROW     100000   // dedicated all-zero fp8 row

#define NB       391      // buckets of 256 dst nodes (391*256 = 100096)
#define CAPB     4608     // staging capacity per bucket
#define CHUNK    8000     // edges per binsort block
#define PCHUNK   128      // nodes per pool_partial block

typedef __bf16 bf16x8 __attribute__((ext_vector_type(8)));
typedef float  f32x4  __attribute__((ext_vector_type(4)));
typedef float  f32x2  __attribute__((ext_vector_type(2)));

// ---------------- W transpose + bf16 convert (Wt[n][k]) + zero-row init ----------------
__global__ __launch_bounds__(256) void prepW(const float* __restrict__ W0,
                                             const float* __restrict__ W1,
                                             const float* __restrict__ W2,
                                             __bf16* __restrict__ wt,
                                             unsigned char* __restrict__ Hs) {
    int idx = blockIdx.x * 256 + threadIdx.x;
    if (blockIdx.x == 0 && threadIdx.x < 32)
        ((unsigned int*)(Hs + (size_t)ZROW * 128))[threadIdx.x] = 0u;
    if (idx >= 3 * 16384) return;
    int which = idx >> 14, e = idx & 16383;
    int k = e >> 7, n = e & 127;
    const float* W = (which == 0) ? W0 : ((which == 1) ? W1 : W2);
    wt[which * 16384 + n * 128 + k] = (__bf16)W[k * 128 + n];
}

// ---------------- pass 1: block-local counting sort of edges by dst bucket ----------------
__global__ __launch_bounds__(512) void binsort(const int* __restrict__ ei,
                                               int* __restrict__ gcur,
                                               int* __restrict__ staging) {
    __shared__ int hist[512];
    __shared__ int hscan[512];
    __shared__ int cur[512];
    __shared__ int gofs[512];
    __shared__ uint2 lbuf[CHUNK];   // 64 KB
    int t = threadIdx.x;
    int base = blockIdx.x * CHUNK;

    hist[t] = 0;
    __syncthreads();
    for (int i = t; i < CHUNK; i += 512)
        atomicAdd(&hist[ei[N_EDGES + base + i] >> 8], 1);
    __syncthreads();
    hscan[t] = hist[t];
    __syncthreads();
    for (int off = 1; off < 512; off <<= 1) {
        int v = (t >= off) ? hscan[t - off] : 0;
        __syncthreads();
        hscan[t] += v;
        __syncthreads();
    }
    int ex = hscan[t] - hist[t];
    cur[t] = ex;
    if (t < NB && hist[t] > 0) {
        int gb = atomicAdd(&gcur[t], hist[t]);
        gofs[t] = t * CAPB + gb - ex;
    }
    __syncthreads();
    for (int i = t; i < CHUNK; i += 512) {
        unsigned src = (unsigned)ei[base + i];
        unsigned dst = (unsigned)ei[N_EDGES + base + i];
        int p = atomicAdd(&cur[dst >> 8], 1);
        lbuf[p] = make_uint2(src, dst);
    }
    __syncthreads();
    for (int i = t; i < CHUNK; i += 512) {
        uint2 v = lbuf[i];
        int b = (int)(v.y >> 8);
        staging[gofs[b] + i] = (int)(((v.y & 255u) << 24) | v.x);
    }
}

// ---------------- pass 2: per-bucket srclist build in LDS, streamed out ----------------
__global__ __launch_bounds__(256) void build_csr(const int* __restrict__ gcur,
                                                 const int* __restrict__ staging,
                                                 int* __restrict__ srclist,
                                                 int* __restrict__ cnt,
                                                 float* __restrict__ dinv) {
    __shared__ int slots[256 * CAP];   // 64 KB
    __shared__ int lcnt[256];
    int t = threadIdx.x, b = blockIdx.x;
    lcnt[t] = 0;
    __syncthreads();
    int cb = gcur[b];
    if (cb > CAPB) cb = CAPB;
    const int* st = staging + b * CAPB;
    for (int i = t; i < cb; i += 256) {
        int v = st[i];
        int ld = ((unsigned)v) >> 24;
        int s = v & 0xFFFFFF;
        int p = atomicAdd(&lcnt[ld], 1);
        if (p < CAP) slots[ld * CAP + p] = s;
    }
    __syncthreads();
    int4* d4 = (int4*)(srclist + (size_t)b * 256 * CAP);
    const int4* s4 = (const int4*)slots;
    for (int j = t; j < 256 * CAP / 4; j += 256) d4[j] = s4[j];
    int node = b * 256 + t;
    if (node < N_NODES) {
        int c = lcnt[t];
        cnt[node] = c;
        dinv[node] = rsqrtf((float)c + 1.0f);
    }
}

// ---------------- GEMM: Hs[row] = fp8(dinv[row] * (A @ W)[row]), bf16 MFMA ----------------
// Operand-swap trick: D = mfma(W-frag, X-frag) gives col(lane&15)=node row,
// row(quad*4+r)=4 CONSECUTIVE features -> pack 4 fp8 bytes/lane -> dword stores.
template <bool A_IS_F32>
__global__ __launch_bounds__(256) void gemm128(const void* __restrict__ Ap,
                                               const __bf16* __restrict__ Wt,
                                               const float* __restrict__ dinv,
                                               unsigned char* __restrict__ Hs) {
    int wid = (blockIdx.x * 256 + threadIdx.x) >> 6;
    if (wid >= N_NODES / 16) return;
    int lane = threadIdx.x & 63;
    int m = lane & 15, q = lane >> 4;
    int rowbase = wid * 16;

    f32x4 acc[8] = {};

#pragma unroll
    for (int ks = 0; ks < 4; ++ks) {
        bf16x8 a;
        if (A_IS_F32) {
            const float* A = (const float*)Ap + (size_t)(rowbase + m) * 128 + ks * 32 + q * 8;
            f32x4 v0 = *(const f32x4*)A;
            f32x4 v1 = *(const f32x4*)(A + 4);
            a[0] = (__bf16)v0[0]; a[1] = (__bf16)v0[1];
            a[2] = (__bf16)v0[2]; a[3] = (__bf16)v0[3];
            a[4] = (__bf16)v1[0]; a[5] = (__bf16)v1[1];
            a[6] = (__bf16)v1[2]; a[7] = (__bf16)v1[3];
        } else {
            a = *(const bf16x8*)((const __bf16*)Ap + (size_t)(rowbase + m) * 128 + ks * 32 + q * 8);
        }
#pragma unroll
        for (int tj = 0; tj < 8; ++tj) {
            bf16x8 b = *(const bf16x8*)(Wt + (tj * 16 + m) * 128 + ks * 32 + q * 8);
            // swapped operands: A-frag = W^T tile, B-frag = X rows
            acc[tj] = __builtin_amdgcn_mfma_f32_16x16x32_bf16(b, a, acc[tj], 0, 0, 0);
        }
    }

    // D layout (swapped): node = rowbase + m, features tj*16 + q*4 + {0..3}
    float dv = dinv[rowbase + m];
    unsigned char* rowp = Hs + (size_t)(rowbase + m) * 128 + q * 4;
#pragma unroll
    for (int tj = 0; tj < 8; ++tj) {
        int lo = __builtin_amdgcn_cvt_pk_fp8_f32(acc[tj][0] * dv, acc[tj][1] * dv, 0, false);
        int w  = __builtin_amdgcn_cvt_pk_fp8_f32(acc[tj][2] * dv, acc[tj][3] * dv, lo, true);
        *(unsigned int*)(rowp + tj * 16) = (unsigned int)w;
    }
}

// ---------------- aggregation: one wave per dst node, fp8 gather, pipelined ----------------
// lanes: g = lane>>4 (edge slot), idx = lane&15 (dims idx*8..idx*8+7, 8 B/lane fp8)
template <bool RELU>
__global__ __launch_bounds__(256) void aggregate(const unsigned char* __restrict__ Hs,
                                                 const float* __restrict__ bias,
                                                 const float* __restrict__ dinv,
                                                 const int* __restrict__ cnt,
                                                 const int* __restrict__ srclist,
                                                 __bf16* __restrict__ X) {
    int node = blockIdx.x * 4 + (threadIdx.x >> 6);
    int lane = threadIdx.x & 63;
    int g = lane >> 4;
    int idx = lane & 15;
    float di = dinv[node];
    int deg = cnt[node];
    if (deg > CAP) deg = CAP;
    const int* lst = srclist + (size_t)node * CAP;

    float acc[8] = {0.f, 0.f, 0.f, 0.f, 0.f, 0.f, 0.f, 0.f};

    // depth-1 software pipeline
    int s = (g < deg) ? lst[g] : ZROW;
    uint2 v = *(const uint2*)(Hs + (size_t)s * 128 + idx * 8);
    for (int e = 0; e < deg; e += 4) {
        int en = e + 4 + g;
        int sn = (en < deg) ? lst[en & 63] : ZROW;
        uint2 vn = *(const uint2*)(Hs + (size_t)sn * 128 + idx * 8);
        f32x2 p0 = __builtin_amdgcn_cvt_pk_f32_fp8(v.x, false);
        f32x2 p1 = __builtin_amdgcn_cvt_pk_f32_fp8(v.x, true);
        f32x2 p2 = __builtin_amdgcn_cvt_pk_f32_fp8(v.y, false);
        f32x2 p3 = __builtin_amdgcn_cvt_pk_f32_fp8(v.y, true);
        acc[0] += p0.x; acc[1] += p0.y; acc[2] += p1.x; acc[3] += p1.y;
        acc[4] += p2.x; acc[5] += p2.y; acc[6] += p3.x; acc[7] += p3.y;
        v = vn;
    }

    // reduce across the 4 edge-groups
#pragma unroll
    for (int j = 0; j < 8; ++j) {
        acc[j] += __shfl_xor(acc[j], 16);
        acc[j] += __shfl_xor(acc[j], 32);
    }

    // self-loop term: + Hs[node] (already scaled by dinv[node])
    uint2 hv = *(const uint2*)(Hs + (size_t)node * 128 + idx * 8);
    f32x2 q0 = __builtin_amdgcn_cvt_pk_f32_fp8(hv.x, false);
    f32x2 q1 = __builtin_amdgcn_cvt_pk_f32_fp8(hv.x, true);
    f32x2 q2 = __builtin_amdgcn_cvt_pk_f32_fp8(hv.y, false);
    f32x2 q3 = __builtin_amdgcn_cvt_pk_f32_fp8(hv.y, true);
    acc[0] += q0.x; acc[1] += q0.y; acc[2] += q1.x; acc[3] += q1.y;
    acc[4] += q2.x; acc[5] += q2.y; acc[6] += q3.x; acc[7] += q3.y;

    f32x4 b0 = *(const f32x4*)(bias + idx * 8);
    f32x4 b1 = *(const f32x4*)(bias + idx * 8 + 4);
    bf16x8 o;
#pragma unroll
    for (int j = 0; j < 8; ++j) {
        float bj = (j < 4) ? b0[j] : b1[j - 4];
        float t = di * acc[j] + bj;
        if (RELU) t = fmaxf(t, 0.f);
        o[j] = (__bf16)t;
    }
    if (g == 0) *(bf16x8*)(X + (size_t)node * 128 + idx * 8) = o;
}

// ---------------- pooling stage 1: per-chunk fp32 partial sums, atomic flush ----------------
__global__ __launch_bounds__(256) void pool_partial(const __bf16* __restrict__ X,
                                                    const int* __restrict__ batch,
                                                    float* __restrict__ sums) {
    int t = threadIdx.x;
    int d = t & 127, half = t >> 7;
    int start = blockIdx.x * PCHUNK;
    int end = start + PCHUNK;
    if (end > N_NODES) end = N_NODES;
    float acc = 0.f;
    int curg = -1;
    for (int i = start + half; i < end; i += 2) {
        int g = batch[i];
        if (g != curg) {
            if (curg >= 0) atomicAdd(&sums[curg * 128 + d], acc);
            acc = 0.f;
            curg = g;
        }
        acc += (float)X[(size_t)i * 128 + d];
    }
    if (curg >= 0) atomicAdd(&sums[curg * 128 + d], acc);
}

// ---------------- pooling stage 2: divide, linear, softmax ----------------
__global__ __launch_bounds__(64) void pool_final(const float* __restrict__ sums,
                                                 const int* __restrict__ batch,
                                                 const float* __restrict__ linW,
                                                 const float* __restrict__ linb,
                                                 float* __restrict__ out) {
    int g = blockIdx.x, lane = threadIdx.x;
    int bnd[2];
#pragma unroll
    for (int k = 0; k < 2; ++k) {
        int target = g + k;
        int lo = 0, hi = N_NODES;
        while (lo < hi) {
            int mid = (lo + hi) >> 1;
            if (batch[mid] < target) lo = mid + 1; else hi = mid;
        }
        bnd[k] = lo;
    }
    float c = fmaxf((float)(bnd[1] - bnd[0]), 1.f);
    float p0 = sums[g * 128 + lane] / c;
    float p1 = sums[g * 128 + 64 + lane] / c;

    float lg[N_CLS];
#pragma unroll
    for (int cc = 0; cc < N_CLS; ++cc) {
        float v = p0 * linW[lane * N_CLS + cc] + p1 * linW[(lane + 64) * N_CLS + cc];
#pragma unroll
        for (int off = 1; off < 64; off <<= 1) v += __shfl_xor(v, off);
        lg[cc] = v + linb[cc];
    }
    float mx = -1e30f;
#pragma unroll
    for (int cc = 0; cc < N_CLS; ++cc) mx = fmaxf(mx, lg[cc]);
    float ssum = 0.f;
#pragma unroll
    for (int cc = 0; cc < N_CLS; ++cc) { lg[cc] = __expf(lg[cc] - mx); ssum += lg[cc]; }
    if (lane < N_CLS) out[g * N_CLS + lane] = lg[lane] / ssum;
}

extern "C" void kernel_launch(void* const* d_in, const int* in_sizes, int n_in,
                              void* d_out, int out_size, void* d_ws, size_t ws_size,
                              hipStream_t stream) {
    const float* x     = (const float*)d_in[0];
    const int*   ei    = (const int*)d_in[1];
    const int*   batch = (const int*)d_in[2];
    const float* W0    = (const float*)d_in[3];
    const float* b0    = (const float*)d_in[4];
    const float* W1    = (const float*)d_in[5];
    const float* b1    = (const float*)d_in[6];
    const float* W2    = (const float*)d_in[7];
    const float* b2    = (const float*)d_in[8];
    const float* linW  = (const float*)d_in[9];
    const float* linb  = (const float*)d_in[10];

    char* ws = (char*)d_ws;
    int*    gcur    = (int*)(ws + 0);             // 2048 B
    float*  sums    = (float*)(ws + 2048);        // 65536 B
    float*  dinv    = (float*)(ws + 67584);       // 400000 B
    int*    cnt     = (int*)(ws + 467584);        // 400000 B
    __bf16* wt      = (__bf16*)(ws + 867584);     // 98304 B
    int*    srclist = (int*)(ws + 965888);        // 25624576 B
    unsigned char* Hs = (unsigned char*)(ws + 26590464); // 12.8 MB fp8 (+ zero row)
    int*    staging = (int*)(ws + 26590464);      // 7.2 MB, aliases Hs (dead before gemm)
    __bf16* xbuf    = (__bf16*)(ws + 52190464);   // 25.6 MB

    hipMemsetAsync(ws, 0, 67584, stream);         // gcur + sums

    prepW<<<192, 256, 0, stream>>>(W0, W1, W2, wt, Hs);   // also zeroes Hs[ZROW]
    binsort<<<200, 512, 0, stream>>>(ei, gcur, staging);
    build_csr<<<NB, 256, 0, stream>>>(gcur, staging, srclist, cnt, dinv);

    // Layer 0
    gemm128<true><<<1563, 256, 0, stream>>>(x, wt, dinv, Hs);
    aggregate<true><<<N_NODES / 4, 256, 0, stream>>>(Hs, b0, dinv, cnt, srclist, xbuf);
    // Layer 1
    gemm128<false><<<1563, 256, 0, stream>>>(xbuf, wt + 16384, dinv, Hs);
    aggregate<true><<<N_NODES / 4, 256, 0, stream>>>(Hs, b1, dinv, cnt, srclist, xbuf);
    // Layer 2 (no relu)
    gemm128<false><<<1563, 256, 0, stream>>>(xbuf, wt + 32768, dinv, Hs);
    aggregate<false><<<N_NODES / 4, 256, 0, stream>>>(Hs, b2, dinv, cnt, srclist, xbuf);

    pool_partial<<<(N_NODES + PCHUNK - 1) / PCHUNK, 256, 0, stream>>>(xbuf, batch, sums);
    pool_final<<<N_GRAPHS, 64, 0, stream>>>(sums, batch, linW, linb, (float*)d_out);
}

// Round 8
// 417.988 us; speedup vs baseline: 1.0416x; 1.0246x over previous
//
#include <hip/hip_runtime.h>
#include <hip/hip_bf16.h>

#define N_NODES  100000
#define N_EDGES  1600000
#define D_FEAT   128
#define N_GRAPHS 128
#define N_CLS    10
#define CAP      64
#define ZROW     100000   // dedicated all-zero fp8 row

#define NB       391      // buckets of 256 dst nodes (391*256 = 100096)
#define CAPB     4608     // staging capacity per bucket
#define CHUNK    4000     // edges per binsort block (400 * 4000 = 1.6M)
#define PCHUNK   128      // nodes per pool_partial block
#define AGG_WAVES 8192    // persistent aggregate waves (2048 blocks)

typedef __bf16 bf16x8 __attribute__((ext_vector_type(8)));
typedef float  f32x4  __attribute__((ext_vector_type(4)));
typedef float  f32x2  __attribute__((ext_vector_type(2)));

// ---------------- W transpose + bf16 convert (Wt[n][k]) + zero-row init ----------------
__global__ __launch_bounds__(256) void prepW(const float* __restrict__ W0,
                                             const float* __restrict__ W1,
                                             const float* __restrict__ W2,
                                             __bf16* __restrict__ wt,
                                             unsigned char* __restrict__ Hs) {
    int idx = blockIdx.x * 256 + threadIdx.x;
    if (blockIdx.x == 0 && threadIdx.x < 32)
        ((unsigned int*)(Hs + (size_t)ZROW * 128))[threadIdx.x] = 0u;
    if (idx >= 3 * 16384) return;
    int which = idx >> 14, e = idx & 16383;
    int k = e >> 7, n = e & 127;
    const float* W = (which == 0) ? W0 : ((which == 1) ? W1 : W2);
    wt[which * 16384 + n * 128 + k] = (__bf16)W[k * 128 + n];
}

// ---------------- pass 1: block-local counting sort of edges by dst bucket ----------------
__global__ __launch_bounds__(512) void binsort(const int* __restrict__ ei,
                                               int* __restrict__ gcur,
                                               int* __restrict__ staging) {
    __shared__ int hist[512];
    __shared__ int hscan[512];
    __shared__ int cur[512];
    __shared__ int gofs[512];
    __shared__ uint2 lbuf[CHUNK];   // 32 KB
    int t = threadIdx.x;
    int base = blockIdx.x * CHUNK;

    hist[t] = 0;
    __syncthreads();
    for (int i = t; i < CHUNK; i += 512)
        atomicAdd(&hist[ei[N_EDGES + base + i] >> 8], 1);
    __syncthreads();
    hscan[t] = hist[t];
    __syncthreads();
    for (int off = 1; off < 512; off <<= 1) {
        int v = (t >= off) ? hscan[t - off] : 0;
        __syncthreads();
        hscan[t] += v;
        __syncthreads();
    }
    int ex = hscan[t] - hist[t];
    cur[t] = ex;
    if (t < NB && hist[t] > 0) {
        int gb = atomicAdd(&gcur[t], hist[t]);
        gofs[t] = t * CAPB + gb - ex;
    }
    __syncthreads();
    for (int i = t; i < CHUNK; i += 512) {
        unsigned src = (unsigned)ei[base + i];
        unsigned dst = (unsigned)ei[N_EDGES + base + i];
        int p = atomicAdd(&cur[dst >> 8], 1);
        lbuf[p] = make_uint2(src, dst);
    }
    __syncthreads();
    for (int i = t; i < CHUNK; i += 512) {
        uint2 v = lbuf[i];
        int b = (int)(v.y >> 8);
        staging[gofs[b] + i] = (int)(((v.y & 255u) << 24) | v.x);
    }
}

// ---------------- pass 2: per-bucket srclist build in LDS, streamed out ----------------
__global__ __launch_bounds__(256) void build_csr(const int* __restrict__ gcur,
                                                 const int* __restrict__ staging,
                                                 int* __restrict__ srclist,
                                                 int* __restrict__ cnt,
                                                 float* __restrict__ dinv) {
    __shared__ int slots[256 * CAP];   // 64 KB
    __shared__ int lcnt[256];
    int t = threadIdx.x, b = blockIdx.x;
    lcnt[t] = 0;
    __syncthreads();
    int cb = gcur[b];
    if (cb > CAPB) cb = CAPB;
    const int* st = staging + b * CAPB;
    for (int i = t; i < cb; i += 256) {
        int v = st[i];
        int ld = ((unsigned)v) >> 24;
        int s = v & 0xFFFFFF;
        int p = atomicAdd(&lcnt[ld], 1);
        if (p < CAP) slots[ld * CAP + p] = s;
    }
    __syncthreads();
    int4* d4 = (int4*)(srclist + (size_t)b * 256 * CAP);
    const int4* s4 = (const int4*)slots;
    for (int j = t; j < 256 * CAP / 4; j += 256) d4[j] = s4[j];
    int node = b * 256 + t;
    if (node < N_NODES) {
        int c = lcnt[t];
        cnt[node] = c;
        dinv[node] = rsqrtf((float)c + 1.0f);
    }
}

// ---------------- GEMM: Hs[row] = fp8(dinv[row] * (A @ W)[row]), bf16 MFMA ----------------
template <bool A_IS_F32>
__global__ __launch_bounds__(256) void gemm128(const void* __restrict__ Ap,
                                               const __bf16* __restrict__ Wt,
                                               const float* __restrict__ dinv,
                                               unsigned char* __restrict__ Hs) {
    int wid = (blockIdx.x * 256 + threadIdx.x) >> 6;
    if (wid >= N_NODES / 16) return;
    int lane = threadIdx.x & 63;
    int m = lane & 15, q = lane >> 4;
    int rowbase = wid * 16;

    f32x4 acc[8] = {};

#pragma unroll
    for (int ks = 0; ks < 4; ++ks) {
        bf16x8 a;
        if (A_IS_F32) {
            const float* A = (const float*)Ap + (size_t)(rowbase + m) * 128 + ks * 32 + q * 8;
            f32x4 v0 = *(const f32x4*)A;
            f32x4 v1 = *(const f32x4*)(A + 4);
            a[0] = (__bf16)v0[0]; a[1] = (__bf16)v0[1];
            a[2] = (__bf16)v0[2]; a[3] = (__bf16)v0[3];
            a[4] = (__bf16)v1[0]; a[5] = (__bf16)v1[1];
            a[6] = (__bf16)v1[2]; a[7] = (__bf16)v1[3];
        } else {
            a = *(const bf16x8*)((const __bf16*)Ap + (size_t)(rowbase + m) * 128 + ks * 32 + q * 8);
        }
#pragma unroll
        for (int tj = 0; tj < 8; ++tj) {
            bf16x8 b = *(const bf16x8*)(Wt + (tj * 16 + m) * 128 + ks * 32 + q * 8);
            // swapped operands: D = (W-tile)^T x X-rows -> features contiguous per lane
            acc[tj] = __builtin_amdgcn_mfma_f32_16x16x32_bf16(b, a, acc[tj], 0, 0, 0);
        }
    }

    // D layout (swapped): node = rowbase + m, features tj*16 + q*4 + {0..3}
    float dv = dinv[rowbase + m];
    unsigned char* rowp = Hs + (size_t)(rowbase + m) * 128 + q * 4;
#pragma unroll
    for (int tj = 0; tj < 8; ++tj) {
        int lo = __builtin_amdgcn_cvt_pk_fp8_f32(acc[tj][0] * dv, acc[tj][1] * dv, 0, false);
        int w  = __builtin_amdgcn_cvt_pk_fp8_f32(acc[tj][2] * dv, acc[tj][3] * dv, lo, true);
        *(unsigned int*)(rowp + tj * 16) = (unsigned int)w;
    }
}

// ---------------- aggregation: persistent waves, depth-2 pipeline, fp8 gather ----------------
// lanes: g = lane>>4 (edge slot), idx = lane&15 (dims idx*8..idx*8+7, 8 B/lane fp8)
template <bool RELU>
__global__ __launch_bounds__(256, 8) void aggregate(const unsigned char* __restrict__ Hs,
                                                    const float* __restrict__ bias,
                                                    const float* __restrict__ dinv,
                                                    const int* __restrict__ cnt,
                                                    const int* __restrict__ srclist,
                                                    __bf16* __restrict__ X) {
    int wid = (blockIdx.x * 256 + threadIdx.x) >> 6;   // 0..AGG_WAVES-1
    int lane = threadIdx.x & 63;
    int g = lane >> 4;
    int idx = lane & 15;

    f32x4 bb0 = *(const f32x4*)(bias + idx * 8);
    f32x4 bb1 = *(const f32x4*)(bias + idx * 8 + 4);

    for (int node = wid; node < N_NODES; node += AGG_WAVES) {
        float di = dinv[node];
        int deg = cnt[node];
        if (deg > CAP) deg = CAP;
        const int* lst = srclist + (size_t)node * CAP;

        float acc[8] = {0.f, 0.f, 0.f, 0.f, 0.f, 0.f, 0.f, 0.f};

        // depth-2 software pipeline: 2 row-loads in flight
        int s0 = (g < deg) ? lst[g] : ZROW;
        int s1 = (4 + g < deg) ? lst[4 + g] : ZROW;
        uint2 v0 = *(const uint2*)(Hs + (size_t)s0 * 128 + idx * 8);
        uint2 v1 = *(const uint2*)(Hs + (size_t)s1 * 128 + idx * 8);
        for (int e = 0; e < deg; e += 4) {
            int en = e + 8 + g;
            int sn = (en < deg) ? lst[en] : ZROW;
            uint2 vn = *(const uint2*)(Hs + (size_t)sn * 128 + idx * 8);
            f32x2 p0 = __builtin_amdgcn_cvt_pk_f32_fp8(v0.x, false);
            f32x2 p1 = __builtin_amdgcn_cvt_pk_f32_fp8(v0.x, true);
            f32x2 p2 = __builtin_amdgcn_cvt_pk_f32_fp8(v0.y, false);
            f32x2 p3 = __builtin_amdgcn_cvt_pk_f32_fp8(v0.y, true);
            acc[0] += p0.x; acc[1] += p0.y; acc[2] += p1.x; acc[3] += p1.y;
            acc[4] += p2.x; acc[5] += p2.y; acc[6] += p3.x; acc[7] += p3.y;
            v0 = v1; v1 = vn;
        }

        // reduce across the 4 edge-groups
#pragma unroll
        for (int j = 0; j < 8; ++j) {
            acc[j] += __shfl_xor(acc[j], 16);
            acc[j] += __shfl_xor(acc[j], 32);
        }

        // self-loop term: + Hs[node] (already scaled by dinv[node])
        uint2 hv = *(const uint2*)(Hs + (size_t)node * 128 + idx * 8);
        f32x2 q0 = __builtin_amdgcn_cvt_pk_f32_fp8(hv.x, false);
        f32x2 q1 = __builtin_amdgcn_cvt_pk_f32_fp8(hv.x, true);
        f32x2 q2 = __builtin_amdgcn_cvt_pk_f32_fp8(hv.y, false);
        f32x2 q3 = __builtin_amdgcn_cvt_pk_f32_fp8(hv.y, true);
        acc[0] += q0.x; acc[1] += q0.y; acc[2] += q1.x; acc[3] += q1.y;
        acc[4] += q2.x; acc[5] += q2.y; acc[6] += q3.x; acc[7] += q3.y;

        bf16x8 o;
#pragma unroll
        for (int j = 0; j < 8; ++j) {
            float bj = (j < 4) ? bb0[j] : bb1[j - 4];
            float t = di * acc[j] + bj;
            if (RELU) t = fmaxf(t, 0.f);
            o[j] = (__bf16)t;
        }
        if (g == 0) *(bf16x8*)(X + (size_t)node * 128 + idx * 8) = o;
    }
}

// ---------------- pooling stage 1: per-chunk fp32 partial sums, atomic flush ----------------
__global__ __launch_bounds__(256) void pool_partial(const __bf16* __restrict__ X,
                                                    const int* __restrict__ batch,
                                                    float* __restrict__ sums) {
    int t = threadIdx.x;
    int d = t & 127, half = t >> 7;
    int start = blockIdx.x * PCHUNK;
    int end = start + PCHUNK;
    if (end > N_NODES) end = N_NODES;
    float acc = 0.f;
    int curg = -1;
    for (int i = start + half; i < end; i += 2) {
        int g = batch[i];
        if (g != curg) {
            if (curg >= 0) atomicAdd(&sums[curg * 128 + d], acc);
            acc = 0.f;
            curg = g;
        }
        acc += (float)X[(size_t)i * 128 + d];
    }
    if (curg >= 0) atomicAdd(&sums[curg * 128 + d], acc);
}

// ---------------- pooling stage 2: divide, linear, softmax ----------------
__global__ __launch_bounds__(64) void pool_final(const float* __restrict__ sums,
                                                 const int* __restrict__ batch,
                                                 const float* __restrict__ linW,
                                                 const float* __restrict__ linb,
                                                 float* __restrict__ out) {
    int g = blockIdx.x, lane = threadIdx.x;
    int bnd[2];
#pragma unroll
    for (int k = 0; k < 2; ++k) {
        int target = g + k;
        int lo = 0, hi = N_NODES;
        while (lo < hi) {
            int mid = (lo + hi) >> 1;
            if (batch[mid] < target) lo = mid + 1; else hi = mid;
        }
        bnd[k] = lo;
    }
    float c = fmaxf((float)(bnd[1] - bnd[0]), 1.f);
    float p0 = sums[g * 128 + lane] / c;
    float p1 = sums[g * 128 + 64 + lane] / c;

    float lg[N_CLS];
#pragma unroll
    for (int cc = 0; cc < N_CLS; ++cc) {
        float v = p0 * linW[lane * N_CLS + cc] + p1 * linW[(lane + 64) * N_CLS + cc];
#pragma unroll
        for (int off = 1; off < 64; off <<= 1) v += __shfl_xor(v, off);
        lg[cc] = v + linb[cc];
    }
    float mx = -1e30f;
#pragma unroll
    for (int cc = 0; cc < N_CLS; ++cc) mx = fmaxf(mx, lg[cc]);
    float ssum = 0.f;
#pragma unroll
    for (int cc = 0; cc < N_CLS; ++cc) { lg[cc] = __expf(lg[cc] - mx); ssum += lg[cc]; }
    if (lane < N_CLS) out[g * N_CLS + lane] = lg[lane] / ssum;
}

extern "C" void kernel_launch(void* const* d_in, const int* in_sizes, int n_in,
                              void* d_out, int out_size, void* d_ws, size_t ws_size,
                              hipStream_t stream) {
    const float* x     = (const float*)d_in[0];
    const int*   ei    = (const int*)d_in[1];
    const int*   batch = (const int*)d_in[2];
    const float* W0    = (const float*)d_in[3];
    const float* b0    = (const float*)d_in[4];
    const float* W1    = (const float*)d_in[5];
    const float* b1    = (const float*)d_in[6];
    const float* W2    = (const float*)d_in[7];
    const float* b2    = (const float*)d_in[8];
    const float* linW  = (const float*)d_in[9];
    const float* linb  = (const float*)d_in[10];

    char* ws = (char*)d_ws;
    int*    gcur    = (int*)(ws + 0);             // 2048 B
    float*  sums    = (float*)(ws + 2048);        // 65536 B
    float*  dinv    = (float*)(ws + 67584);       // 400000 B
    int*    cnt     = (int*)(ws + 467584);        // 400000 B
    __bf16* wt      = (__bf16*)(ws + 867584);     // 98304 B
    int*    srclist = (int*)(ws + 965888);        // 25624576 B
    unsigned char* Hs = (unsigned char*)(ws + 26590464); // 12.8 MB fp8 (+ zero row)
    int*    staging = (int*)(ws + 26590464);      // 7.2 MB, aliases Hs (dead before gemm)
    __bf16* xbuf    = (__bf16*)(ws + 52190464);   // 25.6 MB

    hipMemsetAsync(ws, 0, 67584, stream);         // gcur + sums

    prepW<<<192, 256, 0, stream>>>(W0, W1, W2, wt, Hs);   // also zeroes Hs[ZROW]
    binsort<<<N_EDGES / CHUNK, 512, 0, stream>>>(ei, gcur, staging);
    build_csr<<<NB, 256, 0, stream>>>(gcur, staging, srclist, cnt, dinv);

    // Layer 0
    gemm128<true><<<1563, 256, 0, stream>>>(x, wt, dinv, Hs);
    aggregate<true><<<AGG_WAVES / 4, 256, 0, stream>>>(Hs, b0, dinv, cnt, srclist, xbuf);
    // Layer 1
    gemm128<false><<<1563, 256, 0, stream>>>(xbuf, wt + 16384, dinv, Hs);
    aggregate<true><<<AGG_WAVES / 4, 256, 0, stream>>>(Hs, b1, dinv, cnt, srclist, xbuf);
    // Layer 2 (no relu)
    gemm128<false><<<1563, 256, 0, stream>>>(xbuf, wt + 32768, dinv, Hs);
    aggregate<false><<<AGG_WAVES / 4, 256, 0, stream>>>(Hs, b2, dinv, cnt, srclist, xbuf);

    pool_partial<<<(N_NODES + PCHUNK - 1) / PCHUNK, 256, 0, stream>>>(xbuf, batch, sums);
    pool_final<<<N_GRAPHS, 64, 0, stream>>>(sums, batch, linW, linb, (float*)d_out);
}

// Round 9
// 391.971 us; speedup vs baseline: 1.1107x; 1.0664x over previous
//
#include <hip/hip_runtime.h>
#include <hip/hip_bf16.h>

#define N_NODES  100000
#define N_EDGES  1600000
#define D_FEAT   128
#define N_GRAPHS 128
#define N_CLS    10
#define CAP      64
#define ZROW     100000   // dedicated all-zero fp8 row

#define NB       391      // buckets of 256 dst nodes (391*256 = 100096)
#define CAPB     4608     // staging capacity per bucket
#define CHUNK    4000     // edges per binsort block (400 * 4000 = 1.6M)
#define PCHUNK   128      // nodes per pool_partial block
#define AGG_WAVES 8192    // persistent aggregate waves (2048 blocks)

typedef __bf16 bf16x8 __attribute__((ext_vector_type(8)));
typedef float  f32x4  __attribute__((ext_vector_type(4)));
typedef float  f32x2  __attribute__((ext_vector_type(2)));

// ---------------- W transpose + bf16 convert (Wt[n][k]) + zero-row init ----------------
__global__ __launch_bounds__(256) void prepW(const float* __restrict__ W0,
                                             const float* __restrict__ W1,
                                             const float* __restrict__ W2,
                                             __bf16* __restrict__ wt,
                                             unsigned char* __restrict__ Hs) {
    int idx = blockIdx.x * 256 + threadIdx.x;
    if (blockIdx.x == 0 && threadIdx.x < 32)
        ((unsigned int*)(Hs + (size_t)ZROW * 128))[threadIdx.x] = 0u;
    if (idx >= 3 * 16384) return;
    int which = idx >> 14, e = idx & 16383;
    int k = e >> 7, n = e & 127;
    const float* W = (which == 0) ? W0 : ((which == 1) ? W1 : W2);
    wt[which * 16384 + n * 128 + k] = (__bf16)W[k * 128 + n];
}

// ---------------- pass 1: block-local counting sort of edges by dst bucket ----------------
__global__ __launch_bounds__(512) void binsort(const int* __restrict__ ei,
                                               int* __restrict__ gcur,
                                               int* __restrict__ staging) {
    __shared__ int hist[512];
    __shared__ int hscan[512];
    __shared__ int cur[512];
    __shared__ int gofs[512];
    __shared__ uint2 lbuf[CHUNK];   // 32 KB
    int t = threadIdx.x;
    int base = blockIdx.x * CHUNK;

    hist[t] = 0;
    __syncthreads();
    for (int i = t; i < CHUNK; i += 512)
        atomicAdd(&hist[ei[N_EDGES + base + i] >> 8], 1);
    __syncthreads();
    hscan[t] = hist[t];
    __syncthreads();
    for (int off = 1; off < 512; off <<= 1) {
        int v = (t >= off) ? hscan[t - off] : 0;
        __syncthreads();
        hscan[t] += v;
        __syncthreads();
    }
    int ex = hscan[t] - hist[t];
    cur[t] = ex;
    if (t < NB && hist[t] > 0) {
        int gb = atomicAdd(&gcur[t], hist[t]);
        gofs[t] = t * CAPB + gb - ex;
    }
    __syncthreads();
    for (int i = t; i < CHUNK; i += 512) {
        unsigned src = (unsigned)ei[base + i];
        unsigned dst = (unsigned)ei[N_EDGES + base + i];
        int p = atomicAdd(&cur[dst >> 8], 1);
        lbuf[p] = make_uint2(src, dst);
    }
    __syncthreads();
    for (int i = t; i < CHUNK; i += 512) {
        uint2 v = lbuf[i];
        int b = (int)(v.y >> 8);
        staging[gofs[b] + i] = (int)(((v.y & 255u) << 24) | v.x);
    }
}

// ---------------- pass 2: per-bucket srclist build in LDS, streamed out ----------------
// Slot 0 of each node's list = the node itself (self-loop edge); lcnt starts at 1,
// so lcnt == true_deg + 1 and dinv = rsqrt(lcnt) exactly.
__global__ __launch_bounds__(256) void build_csr(const int* __restrict__ gcur,
                                                 const int* __restrict__ staging,
                                                 int* __restrict__ srclist,
                                                 int* __restrict__ cnt,
                                                 float* __restrict__ dinv) {
    __shared__ int slots[256 * CAP];   // 64 KB
    __shared__ int lcnt[256];
    int t = threadIdx.x, b = blockIdx.x;
    lcnt[t] = 1;
    slots[t * CAP] = b * 256 + t;      // self edge at slot 0
    __syncthreads();
    int cb = gcur[b];
    if (cb > CAPB) cb = CAPB;
    const int* st = staging + b * CAPB;
    for (int i = t; i < cb; i += 256) {
        int v = st[i];
        int ld = ((unsigned)v) >> 24;
        int s = v & 0xFFFFFF;
        int p = atomicAdd(&lcnt[ld], 1);
        if (p < CAP) slots[ld * CAP + p] = s;
    }
    __syncthreads();
    int4* d4 = (int4*)(srclist + (size_t)b * 256 * CAP);
    const int4* s4 = (const int4*)slots;
    for (int j = t; j < 256 * CAP / 4; j += 256) d4[j] = s4[j];
    int node = b * 256 + t;
    if (node < N_NODES) {
        int c = lcnt[t];
        if (c > CAP) c = CAP;
        cnt[node] = c;                       // includes self
        dinv[node] = rsqrtf((float)c);       // rsqrt(deg_true + 1)
    }
}

// ---------------- GEMM: Hs[row] = fp8(dinv[row] * (A @ W)[row]), bf16 MFMA ----------------
template <bool A_IS_F32>
__global__ __launch_bounds__(256) void gemm128(const void* __restrict__ Ap,
                                               const __bf16* __restrict__ Wt,
                                               const float* __restrict__ dinv,
                                               unsigned char* __restrict__ Hs) {
    int wid = (blockIdx.x * 256 + threadIdx.x) >> 6;
    if (wid >= N_NODES / 16) return;
    int lane = threadIdx.x & 63;
    int m = lane & 15, q = lane >> 4;
    int rowbase = wid * 16;

    f32x4 acc[8] = {};

#pragma unroll
    for (int ks = 0; ks < 4; ++ks) {
        bf16x8 a;
        if (A_IS_F32) {
            const float* A = (const float*)Ap + (size_t)(rowbase + m) * 128 + ks * 32 + q * 8;
            f32x4 v0 = *(const f32x4*)A;
            f32x4 v1 = *(const f32x4*)(A + 4);
            a[0] = (__bf16)v0[0]; a[1] = (__bf16)v0[1];
            a[2] = (__bf16)v0[2]; a[3] = (__bf16)v0[3];
            a[4] = (__bf16)v1[0]; a[5] = (__bf16)v1[1];
            a[6] = (__bf16)v1[2]; a[7] = (__bf16)v1[3];
        } else {
            a = *(const bf16x8*)((const __bf16*)Ap + (size_t)(rowbase + m) * 128 + ks * 32 + q * 8);
        }
#pragma unroll
        for (int tj = 0; tj < 8; ++tj) {
            bf16x8 b = *(const bf16x8*)(Wt + (tj * 16 + m) * 128 + ks * 32 + q * 8);
            // swapped operands: D = (W-tile)^T x X-rows -> features contiguous per lane
            acc[tj] = __builtin_amdgcn_mfma_f32_16x16x32_bf16(b, a, acc[tj], 0, 0, 0);
        }
    }

    // D layout (swapped): node = rowbase + m, features tj*16 + q*4 + {0..3}
    float dv = dinv[rowbase + m];
    unsigned char* rowp = Hs + (size_t)(rowbase + m) * 128 + q * 4;
#pragma unroll
    for (int tj = 0; tj < 8; ++tj) {
        int lo = __builtin_amdgcn_cvt_pk_fp8_f32(acc[tj][0] * dv, acc[tj][1] * dv, 0, false);
        int w  = __builtin_amdgcn_cvt_pk_fp8_f32(acc[tj][2] * dv, acc[tj][3] * dv, lo, true);
        *(unsigned int*)(rowp + tj * 16) = (unsigned int)w;
    }
}

// ---------------- aggregation: register-resident src list, depth-3 gather pipeline ----------------
// lanes: g = lane>>4 (edge slot), idx = lane&15 (dims idx*8..idx*8+7, 8 B/lane fp8).
// Whole 64-entry list loaded once (lane L holds entry L); per-iter index via __shfl.
template <bool RELU>
__global__ __launch_bounds__(256, 8) void aggregate(const unsigned char* __restrict__ Hs,
                                                    const float* __restrict__ bias,
                                                    const float* __restrict__ dinv,
                                                    const int* __restrict__ cnt,
                                                    const int* __restrict__ srclist,
                                                    __bf16* __restrict__ X) {
    int wid = (blockIdx.x * 256 + threadIdx.x) >> 6;   // 0..AGG_WAVES-1
    int lane = threadIdx.x & 63;
    int g = lane >> 4;
    int idx = lane & 15;
    unsigned rowoff = (unsigned)idx * 8;

    f32x4 bb0 = *(const f32x4*)(bias + idx * 8);
    f32x4 bb1 = *(const f32x4*)(bias + idx * 8 + 4);

    for (int node = wid; node < N_NODES; node += AGG_WAVES) {
        float di = dinv[node];
        int deg = cnt[node];                                  // includes self, in [1, CAP]
        int myS = srclist[(size_t)node * CAP + lane];         // full list in registers

        f32x2 acc[4] = {};

        auto fetch = [&](int e) -> uint2 {
            int en = e + g;
            int se = __shfl(myS, en);
            se = (en < deg) ? se : ZROW;
            unsigned off = ((unsigned)se << 7) + rowoff;
            return *(const uint2*)(Hs + off);
        };

        // depth-3 pipeline: 3 row-gathers in flight, no dependent index loads
        uint2 v0 = fetch(0);
        uint2 v1 = fetch(4);
        uint2 v2 = fetch(8);
        for (int e = 0; e < deg; e += 4) {
            uint2 vn = fetch(e + 12);
            acc[0] += __builtin_amdgcn_cvt_pk_f32_fp8(v0.x, false);
            acc[1] += __builtin_amdgcn_cvt_pk_f32_fp8(v0.x, true);
            acc[2] += __builtin_amdgcn_cvt_pk_f32_fp8(v0.y, false);
            acc[3] += __builtin_amdgcn_cvt_pk_f32_fp8(v0.y, true);
            v0 = v1; v1 = v2; v2 = vn;
        }

        // reduce across the 4 edge-groups (lane bits 4,5)
        float a[8];
#pragma unroll
        for (int j = 0; j < 4; ++j) { a[2 * j] = acc[j][0]; a[2 * j + 1] = acc[j][1]; }
#pragma unroll
        for (int j = 0; j < 8; ++j) {
            a[j] += __shfl_xor(a[j], 16);
            a[j] += __shfl_xor(a[j], 32);
        }

        bf16x8 o;
#pragma unroll
        for (int j = 0; j < 8; ++j) {
            float bj = (j < 4) ? bb0[j] : bb1[j - 4];
            float t = di * a[j] + bj;
            if (RELU) t = fmaxf(t, 0.f);
            o[j] = (__bf16)t;
        }
        if (g == 0) *(bf16x8*)(X + (size_t)node * 128 + idx * 8) = o;
    }
}

// ---------------- pooling stage 1: per-chunk fp32 partial sums, atomic flush ----------------
__global__ __launch_bounds__(256) void pool_partial(const __bf16* __restrict__ X,
                                                    const int* __restrict__ batch,
                                                    float* __restrict__ sums) {
    int t = threadIdx.x;
    int d = t & 127, half = t >> 7;
    int start = blockIdx.x * PCHUNK;
    int end = start + PCHUNK;
    if (end > N_NODES) end = N_NODES;
    float acc = 0.f;
    int curg = -1;
    for (int i = start + half; i < end; i += 2) {
        int g = batch[i];
        if (g != curg) {
            if (curg >= 0) atomicAdd(&sums[curg * 128 + d], acc);
            acc = 0.f;
            curg = g;
        }
        acc += (float)X[(size_t)i * 128 + d];
    }
    if (curg >= 0) atomicAdd(&sums[curg * 128 + d], acc);
}

// ---------------- pooling stage 2: divide, linear, softmax ----------------
__global__ __launch_bounds__(64) void pool_final(const float* __restrict__ sums,
                                                 const int* __restrict__ batch,
                                                 const float* __restrict__ linW,
                                                 const float* __restrict__ linb,
                                                 float* __restrict__ out) {
    int g = blockIdx.x, lane = threadIdx.x;
    int bnd[2];
#pragma unroll
    for (int k = 0; k < 2; ++k) {
        int target = g + k;
        int lo = 0, hi = N_NODES;
        while (lo < hi) {
            int mid = (lo + hi) >> 1;
            if (batch[mid] < target) lo = mid + 1; else hi = mid;
        }
        bnd[k] = lo;
    }
    float c = fmaxf((float)(bnd[1] - bnd[0]), 1.f);
    float p0 = sums[g * 128 + lane] / c;
    float p1 = sums[g * 128 + 64 + lane] / c;

    float lg[N_CLS];
#pragma unroll
    for (int cc = 0; cc < N_CLS; ++cc) {
        float v = p0 * linW[lane * N_CLS + cc] + p1 * linW[(lane + 64) * N_CLS + cc];
#pragma unroll
        for (int off = 1; off < 64; off <<= 1) v += __shfl_xor(v, off);
        lg[cc] = v + linb[cc];
    }
    float mx = -1e30f;
#pragma unroll
    for (int cc = 0; cc < N_CLS; ++cc) mx = fmaxf(mx, lg[cc]);
    float ssum = 0.f;
#pragma unroll
    for (int cc = 0; cc < N_CLS; ++cc) { lg[cc] = __expf(lg[cc] - mx); ssum += lg[cc]; }
    if (lane < N_CLS) out[g * N_CLS + lane] = lg[lane] / ssum;
}

extern "C" void kernel_launch(void* const* d_in, const int* in_sizes, int n_in,
                              void* d_out, int out_size, void* d_ws, size_t ws_size,
                              hipStream_t stream) {
    const float* x     = (const float*)d_in[0];
    const int*   ei    = (const int*)d_in[1];
    const int*   batch = (const int*)d_in[2];
    const float* W0    = (const float*)d_in[3];
    const float* b0    = (const float*)d_in[4];
    const float* W1    = (const float*)d_in[5];
    const float* b1    = (const float*)d_in[6];
    const float* W2    = (const float*)d_in[7];
    const float* b2    = (const float*)d_in[8];
    const float* linW  = (const float*)d_in[9];
    const float* linb  = (const float*)d_in[10];

    char* ws = (char*)d_ws;
    int*    gcur    = (int*)(ws + 0);             // 2048 B
    float*  sums    = (float*)(ws + 2048);        // 65536 B
    float*  dinv    = (float*)(ws + 67584);       // 400000 B
    int*    cnt     = (int*)(ws + 467584);        // 400000 B
    __bf16* wt      = (__bf16*)(ws + 867584);     // 98304 B
    int*    srclist = (int*)(ws + 965888);        // 25624576 B
    unsigned char* Hs = (unsigned char*)(ws + 26590464); // 12.8 MB fp8 (+ zero row)
    int*    staging = (int*)(ws + 26590464);      // 7.2 MB, aliases Hs (dead before gemm)
    __bf16* xbuf    = (__bf16*)(ws + 52190464);   // 25.6 MB

    hipMemsetAsync(ws, 0, 67584, stream);         // gcur + sums

    prepW<<<192, 256, 0, stream>>>(W0, W1, W2, wt, Hs);   // also zeroes Hs[ZROW]
    binsort<<<N_EDGES / CHUNK, 512, 0, stream>>>(ei, gcur, staging);
    build_csr<<<NB, 256, 0, stream>>>(gcur, staging, srclist, cnt, dinv);

    // Layer 0
    gemm128<true><<<1563, 256, 0, stream>>>(x, wt, dinv, Hs);
    aggregate<true><<<AGG_WAVES / 4, 256, 0, stream>>>(Hs, b0, dinv, cnt, srclist, xbuf);
    // Layer 1
    gemm128<false><<<1563, 256, 0, stream>>>(xbuf, wt + 16384, dinv, Hs);
    aggregate<true><<<AGG_WAVES / 4, 256, 0, stream>>>(Hs, b1, dinv, cnt, srclist, xbuf);
    // Layer 2 (no relu)
    gemm128<false><<<1563, 256, 0, stream>>>(xbuf, wt + 32768, dinv, Hs);
    aggregate<false><<<AGG_WAVES / 4, 256, 0, stream>>>(Hs, b2, dinv, cnt, srclist, xbuf);

    pool_partial<<<(N_NODES + PCHUNK - 1) / PCHUNK, 256, 0, stream>>>(xbuf, batch, sums);
    pool_final<<<N_GRAPHS, 64, 0, stream>>>(sums, batch, linW, linb, (float*)d_out);
}

// Round 10
// 332.253 us; speedup vs baseline: 1.3103x; 1.1797x over previous
//
#include <hip/hip_runtime.h>
#include <hip/hip_bf16.h>

#define N_NODES  100000
#define N_EDGES  1600000
#define D_FEAT   128
#define N_GRAPHS 128
#define N_CLS    10
#define CAP      64
#define ZROW     100000   // dedicated all-zero fp8 row

#define NB       391      // buckets of 256 dst nodes (391*256 = 100096)
#define CAPB     4608     // staging capacity per bucket
#define CHUNK    4000     // edges per binsort block (400 * 4000 = 1.6M)
#define PCHUNK   128      // nodes per pool_partial block
#define AGG_WAVES 8192    // persistent aggregate waves (2048 blocks)
#define WPAD     136      // padded LDS row stride for Wt (breaks bank aliasing)

typedef __bf16 bf16x8 __attribute__((ext_vector_type(8)));
typedef float  f32x4  __attribute__((ext_vector_type(4)));
typedef float  f32x2  __attribute__((ext_vector_type(2)));

// ---------------- W transpose + bf16 convert (Wt[n][k]) + zero-row init ----------------
__global__ __launch_bounds__(256) void prepW(const float* __restrict__ W0,
                                             const float* __restrict__ W1,
                                             const float* __restrict__ W2,
                                             __bf16* __restrict__ wt,
                                             unsigned char* __restrict__ Hs) {
    int idx = blockIdx.x * 256 + threadIdx.x;
    if (blockIdx.x == 0 && threadIdx.x < 32)
        ((unsigned int*)(Hs + (size_t)ZROW * 128))[threadIdx.x] = 0u;
    if (idx >= 3 * 16384) return;
    int which = idx >> 14, e = idx & 16383;
    int k = e >> 7, n = e & 127;
    const float* W = (which == 0) ? W0 : ((which == 1) ? W1 : W2);
    wt[which * 16384 + n * 128 + k] = (__bf16)W[k * 128 + n];
}

// ---------------- pass 1: block-local counting sort of edges by dst bucket ----------------
__global__ __launch_bounds__(512) void binsort(const int* __restrict__ ei,
                                               int* __restrict__ gcur,
                                               int* __restrict__ staging) {
    __shared__ int hist[512];
    __shared__ int hscan[512];
    __shared__ int cur[512];
    __shared__ int gofs[512];
    __shared__ uint2 lbuf[CHUNK];   // 32 KB
    int t = threadIdx.x;
    int base = blockIdx.x * CHUNK;

    hist[t] = 0;
    __syncthreads();
    for (int i = t; i < CHUNK; i += 512)
        atomicAdd(&hist[ei[N_EDGES + base + i] >> 8], 1);
    __syncthreads();
    hscan[t] = hist[t];
    __syncthreads();
    for (int off = 1; off < 512; off <<= 1) {
        int v = (t >= off) ? hscan[t - off] : 0;
        __syncthreads();
        hscan[t] += v;
        __syncthreads();
    }
    int ex = hscan[t] - hist[t];
    cur[t] = ex;
    if (t < NB && hist[t] > 0) {
        int gb = atomicAdd(&gcur[t], hist[t]);
        gofs[t] = t * CAPB + gb - ex;
    }
    __syncthreads();
    for (int i = t; i < CHUNK; i += 512) {
        unsigned src = (unsigned)ei[base + i];
        unsigned dst = (unsigned)ei[N_EDGES + base + i];
        int p = atomicAdd(&cur[dst >> 8], 1);
        lbuf[p] = make_uint2(src, dst);
    }
    __syncthreads();
    for (int i = t; i < CHUNK; i += 512) {
        uint2 v = lbuf[i];
        int b = (int)(v.y >> 8);
        staging[gofs[b] + i] = (int)(((v.y & 255u) << 24) | v.x);
    }
}

// ---------------- pass 2: per-bucket srclist build in LDS, streamed out ----------------
// Slot 0 of each node's list = the node itself (self-loop edge); lcnt starts at 1,
// so lcnt == true_deg + 1 and dinv = rsqrt(lcnt) exactly.
__global__ __launch_bounds__(256) void build_csr(const int* __restrict__ gcur,
                                                 const int* __restrict__ staging,
                                                 int* __restrict__ srclist,
                                                 int* __restrict__ cnt,
                                                 float* __restrict__ dinv) {
    __shared__ int slots[256 * CAP];   // 64 KB
    __shared__ int lcnt[256];
    int t = threadIdx.x, b = blockIdx.x;
    lcnt[t] = 1;
    slots[t * CAP] = b * 256 + t;      // self edge at slot 0
    __syncthreads();
    int cb = gcur[b];
    if (cb > CAPB) cb = CAPB;
    const int* st = staging + b * CAPB;
    for (int i = t; i < cb; i += 256) {
        int v = st[i];
        int ld = ((unsigned)v) >> 24;
        int s = v & 0xFFFFFF;
        int p = atomicAdd(&lcnt[ld], 1);
        if (p < CAP) slots[ld * CAP + p] = s;
    }
    __syncthreads();
    int4* d4 = (int4*)(srclist + (size_t)b * 256 * CAP);
    const int4* s4 = (const int4*)slots;
    for (int j = t; j < 256 * CAP / 4; j += 256) d4[j] = s4[j];
    int node = b * 256 + t;
    if (node < N_NODES) {
        int c = lcnt[t];
        if (c > CAP) c = CAP;
        cnt[node] = c;                       // includes self
        dinv[node] = rsqrtf((float)c);       // rsqrt(deg_true + 1)
    }
}

// ---------------- GEMM: Hs[row] = fp8(dinv[row] * (A @ W)[row]), bf16 MFMA ----------------
// Wt staged in LDS (padded rows), A fragments prefetched -> no serialized VMEM in K-loop.
template <bool A_IS_F32>
__global__ __launch_bounds__(256) void gemm128(const void* __restrict__ Ap,
                                               const __bf16* __restrict__ Wt,
                                               const float* __restrict__ dinv,
                                               unsigned char* __restrict__ Hs) {
    __shared__ __bf16 wlds[128 * WPAD];   // ~34 KB
    int t = threadIdx.x;
    int wid = (blockIdx.x * 256 + t) >> 6;
    int lane = t & 63;
    int m = lane & 15, q = lane >> 4;
    int rowbase = wid * 16;
    bool active = wid < N_NODES / 16;

    // cooperative Wt -> LDS (2048 x 16B, rows padded to WPAD elements)
    {
        const bf16x8* src = (const bf16x8*)Wt;
        for (int j = t; j < 2048; j += 256) {
            int r = j >> 4, c = (j & 15) * 8;
            *(bf16x8*)(wlds + r * WPAD + c) = src[j];
        }
    }

    // prefetch all A fragments (independent global loads) before the barrier
    bf16x8 afrag[4];
    float dv = 0.f;
    if (active) {
        dv = dinv[rowbase + m];
        if (A_IS_F32) {
            const float* A = (const float*)Ap + (size_t)(rowbase + m) * 128 + q * 8;
            f32x4 v[8];
#pragma unroll
            for (int ks = 0; ks < 4; ++ks) {
                v[2 * ks]     = *(const f32x4*)(A + ks * 32);
                v[2 * ks + 1] = *(const f32x4*)(A + ks * 32 + 4);
            }
#pragma unroll
            for (int ks = 0; ks < 4; ++ks)
#pragma unroll
                for (int j = 0; j < 4; ++j) {
                    afrag[ks][j]     = (__bf16)v[2 * ks][j];
                    afrag[ks][4 + j] = (__bf16)v[2 * ks + 1][j];
                }
        } else {
            const __bf16* A = (const __bf16*)Ap + (size_t)(rowbase + m) * 128 + q * 8;
#pragma unroll
            for (int ks = 0; ks < 4; ++ks)
                afrag[ks] = *(const bf16x8*)(A + ks * 32);
        }
    }
    __syncthreads();
    if (!active) return;

    f32x4 acc[8] = {};
#pragma unroll
    for (int ks = 0; ks < 4; ++ks) {
#pragma unroll
        for (int tj = 0; tj < 8; ++tj) {
            bf16x8 b = *(const bf16x8*)(wlds + (tj * 16 + m) * WPAD + ks * 32 + q * 8);
            // swapped operands: D = (W-tile)^T x X-rows -> features contiguous per lane
            acc[tj] = __builtin_amdgcn_mfma_f32_16x16x32_bf16(b, afrag[ks], acc[tj], 0, 0, 0);
        }
    }

    // D layout (swapped): node = rowbase + m, features tj*16 + q*4 + {0..3}
    unsigned char* rowp = Hs + (size_t)(rowbase + m) * 128 + q * 4;
#pragma unroll
    for (int tj = 0; tj < 8; ++tj) {
        int lo = __builtin_amdgcn_cvt_pk_fp8_f32(acc[tj][0] * dv, acc[tj][1] * dv, 0, false);
        int w  = __builtin_amdgcn_cvt_pk_fp8_f32(acc[tj][2] * dv, acc[tj][3] * dv, lo, true);
        *(unsigned int*)(rowp + tj * 16) = (unsigned int)w;
    }
}

// ---------------- aggregation: register-resident src list, depth-3 gather pipeline ----------------
template <bool RELU>
__global__ __launch_bounds__(256, 8) void aggregate(const unsigned char* __restrict__ Hs,
                                                    const float* __restrict__ bias,
                                                    const float* __restrict__ dinv,
                                                    const int* __restrict__ cnt,
                                                    const int* __restrict__ srclist,
                                                    __bf16* __restrict__ X) {
    int wid = (blockIdx.x * 256 + threadIdx.x) >> 6;   // 0..AGG_WAVES-1
    int lane = threadIdx.x & 63;
    int g = lane >> 4;
    int idx = lane & 15;
    unsigned rowoff = (unsigned)idx * 8;

    f32x4 bb0 = *(const f32x4*)(bias + idx * 8);
    f32x4 bb1 = *(const f32x4*)(bias + idx * 8 + 4);

    for (int node = wid; node < N_NODES; node += AGG_WAVES) {
        float di = dinv[node];
        int deg = cnt[node];                                  // includes self, in [1, CAP]
        int myS = srclist[(size_t)node * CAP + lane];         // full list in registers

        f32x2 acc[4] = {};

        auto fetch = [&](int e) -> uint2 {
            int en = e + g;
            int se = __shfl(myS, en);
            se = (en < deg) ? se : ZROW;
            unsigned off = ((unsigned)se << 7) + rowoff;
            return *(const uint2*)(Hs + off);
        };

        uint2 v0 = fetch(0);
        uint2 v1 = fetch(4);
        uint2 v2 = fetch(8);
        for (int e = 0; e < deg; e += 4) {
            uint2 vn = fetch(e + 12);
            acc[0] += __builtin_amdgcn_cvt_pk_f32_fp8(v0.x, false);
            acc[1] += __builtin_amdgcn_cvt_pk_f32_fp8(v0.x, true);
            acc[2] += __builtin_amdgcn_cvt_pk_f32_fp8(v0.y, false);
            acc[3] += __builtin_amdgcn_cvt_pk_f32_fp8(v0.y, true);
            v0 = v1; v1 = v2; v2 = vn;
        }

        float a[8];
#pragma unroll
        for (int j = 0; j < 4; ++j) { a[2 * j] = acc[j][0]; a[2 * j + 1] = acc[j][1]; }
#pragma unroll
        for (int j = 0; j < 8; ++j) {
            a[j] += __shfl_xor(a[j], 16);
            a[j] += __shfl_xor(a[j], 32);
        }

        bf16x8 o;
#pragma unroll
        for (int j = 0; j < 8; ++j) {
            float bj = (j < 4) ? bb0[j] : bb1[j - 4];
            float t = di * a[j] + bj;
            if (RELU) t = fmaxf(t, 0.f);
            o[j] = (__bf16)t;
        }
        if (g == 0) *(bf16x8*)(X + (size_t)node * 128 + idx * 8) = o;
    }
}

// ---------------- pooling stage 1: per-chunk fp32 partial sums, atomic flush ----------------
__global__ __launch_bounds__(256) void pool_partial(const __bf16* __restrict__ X,
                                                    const int* __restrict__ batch,
                                                    float* __restrict__ sums) {
    int t = threadIdx.x;
    int d = t & 127, half = t >> 7;
    int start = blockIdx.x * PCHUNK;
    int end = start + PCHUNK;
    if (end > N_NODES) end = N_NODES;
    float acc = 0.f;
    int curg = -1;
    for (int i = start + half; i < end; i += 2) {
        int g = batch[i];
        if (g != curg) {
            if (curg >= 0) atomicAdd(&sums[curg * 128 + d], acc);
            acc = 0.f;
            curg = g;
        }
        acc += (float)X[(size_t)i * 128 + d];
    }
    if (curg >= 0) atomicAdd(&sums[curg * 128 + d], acc);
}

// ---------------- pooling stage 2: divide, linear, softmax ----------------
__global__ __launch_bounds__(64) void pool_final(const float* __restrict__ sums,
                                                 const int* __restrict__ batch,
                                                 const float* __restrict__ linW,
                                                 const float* __restrict__ linb,
                                                 float* __restrict__ out) {
    int g = blockIdx.x, lane = threadIdx.x;
    int bnd[2];
#pragma unroll
    for (int k = 0; k < 2; ++k) {
        int target = g + k;
        int lo = 0, hi = N_NODES;
        while (lo < hi) {
            int mid = (lo + hi) >> 1;
            if (batch[mid] < target) lo = mid + 1; else hi = mid;
        }
        bnd[k] = lo;
    }
    float c = fmaxf((float)(bnd[1] - bnd[0]), 1.f);
    float p0 = sums[g * 128 + lane] / c;
    float p1 = sums[g * 128 + 64 + lane] / c;

    float lg[N_CLS];
#pragma unroll
    for (int cc = 0; cc < N_CLS; ++cc) {
        float v = p0 * linW[lane * N_CLS + cc] + p1 * linW[(lane + 64) * N_CLS + cc];
#pragma unroll
        for (int off = 1; off < 64; off <<= 1) v += __shfl_xor(v, off);
        lg[cc] = v + linb[cc];
    }
    float mx = -1e30f;
#pragma unroll
    for (int cc = 0; cc < N_CLS; ++cc) mx = fmaxf(mx, lg[cc]);
    float ssum = 0.f;
#pragma unroll
    for (int cc = 0; cc < N_CLS; ++cc) { lg[cc] = __expf(lg[cc] - mx); ssum += lg[cc]; }
    if (lane < N_CLS) out[g * N_CLS + lane] = lg[lane] / ssum;
}

extern "C" void kernel_launch(void* const* d_in, const int* in_sizes, int n_in,
                              void* d_out, int out_size, void* d_ws, size_t ws_size,
                              hipStream_t stream) {
    const float* x     = (const float*)d_in[0];
    const int*   ei    = (const int*)d_in[1];
    const int*   batch = (const int*)d_in[2];
    const float* W0    = (const float*)d_in[3];
    const float* b0    = (const float*)d_in[4];
    const float* W1    = (const float*)d_in[5];
    const float* b1    = (const float*)d_in[6];
    const float* W2    = (const float*)d_in[7];
    const float* b2    = (const float*)d_in[8];
    const float* linW  = (const float*)d_in[9];
    const float* linb  = (const float*)d_in[10];

    char* ws = (char*)d_ws;
    int*    gcur    = (int*)(ws + 0);             // 2048 B
    float*  sums    = (float*)(ws + 2048);        // 65536 B
    float*  dinv    = (float*)(ws + 67584);       // 400000 B
    int*    cnt     = (int*)(ws + 467584);        // 400000 B
    __bf16* wt      = (__bf16*)(ws + 867584);     // 98304 B
    int*    srclist = (int*)(ws + 965888);        // 25624576 B
    unsigned char* Hs = (unsigned char*)(ws + 26590464); // 12.8 MB fp8 (+ zero row)
    int*    staging = (int*)(ws + 26590464);      // 7.2 MB, aliases Hs (dead before gemm)
    __bf16* xbuf    = (__bf16*)(ws + 52190464);   // 25.6 MB

    hipMemsetAsync(ws, 0, 67584, stream);         // gcur + sums

    prepW<<<192, 256, 0, stream>>>(W0, W1, W2, wt, Hs);   // also zeroes Hs[ZROW]
    binsort<<<N_EDGES / CHUNK, 512, 0, stream>>>(ei, gcur, staging);
    build_csr<<<NB, 256, 0, stream>>>(gcur, staging, srclist, cnt, dinv);

    // Layer 0
    gemm128<true><<<1563, 256, 0, stream>>>(x, wt, dinv, Hs);
    aggregate<true><<<AGG_WAVES / 4, 256, 0, stream>>>(Hs, b0, dinv, cnt, srclist, xbuf);
    // Layer 1
    gemm128<false><<<1563, 256, 0, stream>>>(xbuf, wt + 16384, dinv, Hs);
    aggregate<true><<<AGG_WAVES / 4, 256, 0, stream>>>(Hs, b1, dinv, cnt, srclist, xbuf);
    // Layer 2 (no relu)
    gemm128<false><<<1563, 256, 0, stream>>>(xbuf, wt + 32768, dinv, Hs);
    aggregate<false><<<AGG_WAVES / 4, 256, 0, stream>>>(Hs, b2, dinv, cnt, srclist, xbuf);

    pool_partial<<<(N_NODES + PCHUNK - 1) / PCHUNK, 256, 0, stream>>>(xbuf, batch, sums);
    pool_final<<<N_GRAPHS, 64, 0, stream>>>(sums, batch, linW, linb, (float*)d_out);
}